// Round 10
// baseline (139.795 us; speedup 1.0000x reference)
//
#include <hip/hip_runtime.h>
#include <hip/hip_bf16.h>
#include <math.h>

// Problem constants (static config in reference)
#define NT      4096              // B*T
#define DD      1024              // D
#define EE      8                 // experts
#define KK      2                 // top-k
#define CAP     1280              // EXP_CAP
#define CBN     (NT * EE * CAP)   // 41,943,040 elements per big output

#define K2T     1024              // K2 threads (16 waves, one block)
#define JPT     (KK * NT / K2T)   // 8 assignments per thread

#define FB      2048              // fill blocks
#define F4TOT   20971520          // (out_size-8)/4 float4 to zero
#define FITER   (F4TOT / (FB * 256))  // 40 float4 per thread, exact cover

typedef float vf4 __attribute__((ext_vector_type(4)));

// System-scope non-temporal store: bypass L2/LLC (write-allocate thrash on a
// 335MB buffer ~1.3x the 256MB LLC is the suspected 4 TB/s hand-fill ceiling).
__device__ __forceinline__ void stream_store_f4(vf4* p, vf4 v) {
    asm volatile("global_store_dwordx4 %0, %1, off sc0 sc1 nt"
                 :: "v"(p), "v"(v) : "memory");
}

// LDS index swizzle (involution): spreads per-thread contiguous walks
// across banks.
__device__ __forceinline__ int swz(int j) { return j ^ ((j >> 5) & 31); }

// ---------------------------------------------------------------------------
// K0: streaming zero-fill of out[8..] via cache-bypass dwordx4 stores.
// Exact cover: 2048 blocks x 256 threads x 40 f4. Wave writes 1KB per instr.
// ---------------------------------------------------------------------------
__global__ __launch_bounds__(256) void stream_zero_kernel(float* __restrict__ out)
{
    const vf4 zv = {0.0f, 0.0f, 0.0f, 0.0f};
    vf4* dst = reinterpret_cast<vf4*>(out + 8);
    size_t i = (size_t)blockIdx.x * 256 + threadIdx.x;
    const size_t stride = (size_t)FB * 256;
    #pragma unroll 4
    for (int k = 0; k < FITER; ++k) {
        stream_store_f4(dst + i, zv);
        i += stride;
    }
}

// ---------------------------------------------------------------------------
// K1: router logits + top-2 + softmax(top-2). Wave per token, w in LDS.
// (validated rounds 2-8, absmax 0)
// ---------------------------------------------------------------------------
__global__ __launch_bounds__(256) void logits_kernel(
    const float* __restrict__ x,        // (NT, D)
    const float* __restrict__ w,        // (E, D)
    int* __restrict__ e0, int* __restrict__ e1,
    float* __restrict__ p0, float* __restrict__ p1)
{
    __shared__ float wl[EE * DD];       // 32 KB

    for (int i = threadIdx.x; i < EE * DD / 4; i += 256)
        reinterpret_cast<float4*>(wl)[i] = reinterpret_cast<const float4*>(w)[i];
    __syncthreads();

    const int wave = threadIdx.x >> 6;
    const int lane = threadIdx.x & 63;
    const int wid  = blockIdx.x * 4 + wave;

    for (int t = wid; t < NT; t += gridDim.x * 4) {
        const float4* xt = reinterpret_cast<const float4*>(x + (size_t)t * DD);
        float acc[EE];
        #pragma unroll
        for (int e = 0; e < EE; ++e) acc[e] = 0.0f;

        #pragma unroll
        for (int ii = 0; ii < DD / 4 / 64; ++ii) {      // 4 iters
            const int i = ii * 64 + lane;
            const float4 xv = xt[i];
            #pragma unroll
            for (int e = 0; e < EE; ++e) {
                const float4 wv = reinterpret_cast<const float4*>(wl + e * DD)[i];
                acc[e] += xv.x * wv.x + xv.y * wv.y + xv.z * wv.z + xv.w * wv.w;
            }
        }

        #pragma unroll
        for (int e = 0; e < EE; ++e) {
            float v = acc[e];
            #pragma unroll
            for (int off = 32; off > 0; off >>= 1) v += __shfl_xor(v, off);
            acc[e] = v;
        }

        if (lane == 0) {
            int b0 = 0; float l0 = acc[0];
            #pragma unroll
            for (int e = 1; e < EE; ++e) { if (acc[e] > l0) { l0 = acc[e]; b0 = e; } }
            int b1 = -1; float l1 = -INFINITY;
            #pragma unroll
            for (int e = 0; e < EE; ++e) { if (e != b0 && acc[e] > l1) { l1 = acc[e]; b1 = e; } }

            const float z  = expf(l1 - l0);     // l1 <= l0
            const float pa = 1.0f / (1.0f + z);
            const float pb = z * pa;

            e0[t] = b0; e1[t] = b1;
            p0[t] = pa; p1[t] = pb;
        }
    }
}

// ---------------------------------------------------------------------------
// K2: fused ordered rank / capacity drop / used_cap / scatter.
// One block, 1024 threads (16 waves). (validated round 8, absmax 0)
// ---------------------------------------------------------------------------
__global__ __launch_bounds__(K2T) void rank_scatter_kernel(
    const int* __restrict__ e0, const int* __restrict__ e1,
    const float* __restrict__ p0, const float* __restrict__ p1,
    float* __restrict__ out)
{
    __shared__ int   se[KK * NT];       // 32 KB, swizzled
    __shared__ float sp[KK * NT];       // 32 KB, swizzled
    __shared__ unsigned long long wsumA[16], wsumB[16];

    const int tid = threadIdx.x;

    // coalesced stage
    #pragma unroll
    for (int k = 0; k < NT / K2T; ++k) {            // 4 iters
        const int i = k * K2T + tid;
        se[swz(i)]      = e0[i];
        se[swz(NT + i)] = e1[i];
        sp[swz(i)]      = p0[i];
        sp[swz(NT + i)] = p1[i];
    }
    __syncthreads();

    const int base = tid * JPT;
    unsigned long long ca = 0ull, cb = 0ull;        // experts 0-3 / 4-7, 16b fields
    #pragma unroll
    for (int i = 0; i < JPT; ++i) {
        const int e = se[swz(base + i)];
        if (e < 4) ca += 1ull << (16 * e);
        else       cb += 1ull << (16 * (e - 4));
    }

    // intra-wave inclusive scan
    unsigned long long sa = ca, sb = cb;
    #pragma unroll
    for (int off = 1; off < 64; off <<= 1) {
        const unsigned long long ta = __shfl_up(sa, off);
        const unsigned long long tb = __shfl_up(sb, off);
        if ((tid & 63) >= off) { sa += ta; sb += tb; }
    }
    const int wv = tid >> 6;                        // 0..15
    if ((tid & 63) == 63) { wsumA[wv] = sa; wsumB[wv] = sb; }
    __syncthreads();

    unsigned long long preA = 0ull, preB = 0ull;
    #pragma unroll
    for (int k = 0; k < 16; ++k) {
        if (k < wv) { preA += wsumA[k]; preB += wsumB[k]; }
    }
    unsigned long long ra = preA + sa - ca;         // exclusive prefix, this thread
    unsigned long long rb = preB + sb - cb;

    // replay in ascending j order + scatter
    #pragma unroll
    for (int i = 0; i < JPT; ++i) {
        const int j = base + i;
        const int e = se[swz(j)];
        int rank;
        if (e < 4) { rank = (int)((ra >> (16 * e)) & 0xFFFF);       ra += 1ull << (16 * e); }
        else       { rank = (int)((rb >> (16 * (e - 4))) & 0xFFFF); rb += 1ull << (16 * (e - 4)); }
        if (rank < CAP) {
            const float p = sp[swz(j)];
            if (p != 0.0f) {                        // sec_mask == (cb_weight != 0)
                const int t = j & (NT - 1);
                const size_t idx = (size_t)t * (EE * CAP) + (size_t)e * CAP + (size_t)rank;
                out[8 + idx] = p;
                out[8 + (size_t)CBN + idx] = 1.0f;
            }
        }
    }

    // used_cap
    if (tid < EE) {
        unsigned long long totA = 0ull, totB = 0ull;
        #pragma unroll
        for (int k = 0; k < 16; ++k) { totA += wsumA[k]; totB += wsumB[k]; }
        const int e = tid;
        const int tot = (e < 4) ? (int)((totA >> (16 * e)) & 0xFFFF)
                                : (int)((totB >> (16 * (e - 4))) & 0xFFFF);
        out[e] = (float)((tot < CAP) ? tot : CAP);
    }
}

// ---------------------------------------------------------------------------
extern "C" void kernel_launch(void* const* d_in, const int* in_sizes, int n_in,
                              void* d_out, int out_size, void* d_ws, size_t ws_size,
                              hipStream_t stream) {
    const float* x = (const float*)d_in[0];     // (B,T,D) f32
    const float* w = (const float*)d_in[1];     // (E,D)   f32
    float* out = (float*)d_out;

    char* ws = (char*)d_ws;
    int*   e0 = (int*)(ws);                     // 16 KB
    int*   e1 = (int*)(ws + 16 * 1024);         // 16 KB
    float* p0 = (float*)(ws + 32 * 1024);       // 16 KB
    float* p1 = (float*)(ws + 48 * 1024);       // 16 KB

    // 1) cache-bypass streaming zero of out[8..] (sc0 sc1 nt dwordx4).
    //    Tests the LLC write-allocate-thrash theory for the hand-fill 4 TB/s
    //    ceiling; fill first so its drain overlaps K1/K2's LDS-heavy work.
    stream_zero_kernel<<<FB, 256, 0, stream>>>(out);

    // 2) router logits + top-2 + softmax (512 blocks)
    logits_kernel<<<512, 256, 0, stream>>>(x, w, e0, e1, p0, p1);

    // 3) fused ordered rank + capacity + used_cap + scatter (1 block, 16 waves)
    rank_scatter_kernel<<<1, K2T, 0, stream>>>(e0, e1, p0, p1, out);
}

// Round 11
// 121.134 us; speedup vs baseline: 1.1541x; 1.1541x over previous
//
#include <hip/hip_runtime.h>
#include <hip/hip_bf16.h>
#include <math.h>

// Problem constants (static config in reference)
#define NT      4096              // B*T
#define DD      1024              // D
#define EE      8                 // experts
#define KK      2                 // top-k
#define CAP     1280              // EXP_CAP
#define CBN     (NT * EE * CAP)   // 41,943,040 elements per big output

#define FBLK    81920             // fill blocks: 81920*256 f4 = 20,971,520 exact
#define GB      128               // fused K1K2 blocks
#define BT      1024              // threads per fused block (16 waves)
#define WPB     (BT / 64)         // 16
#define NWAVE   (GB * WPB)        // 2048 waves -> 2 tokens/wave
#define JPT     (KK * NT / BT)    // 8 assignments per thread (K2)

// LDS index swizzle (involution): spreads per-thread contiguous walks
// across banks.
__device__ __forceinline__ int swz(int j) { return j ^ ((j >> 5) & 31); }

// ---------------------------------------------------------------------------
// K0: rocclr-shape fill. No LDS, ~8 VGPR, 256-thread blocks, ONE plain
// float4 store per thread, block = 4KB contiguous, 81920 blocks.
// Tests whether the rocclr fill rate (~7 TB/s) is reachable from HIP source.
// ---------------------------------------------------------------------------
__global__ __launch_bounds__(256) void fill_kernel(float* __restrict__ out)
{
    const size_t i = (size_t)blockIdx.x * 256 + threadIdx.x;
    reinterpret_cast<float4*>(out + 8)[i] = make_float4(0.f, 0.f, 0.f, 0.f);
}

// ---------------------------------------------------------------------------
// K1+K2 fused: logits/top2/softmax on all 128 blocks (2 tokens/wave), then
// the LAST block to arrive (ACQ_REL atomic, validated round 9) runs the
// ordered rank / capacity / used_cap / scatter (1024-thread version,
// validated rounds 8-9, absmax 0).
// ---------------------------------------------------------------------------
__global__ __launch_bounds__(BT) void fused_k1k2_kernel(
    const float* __restrict__ x,        // (NT, D)
    const float* __restrict__ w,        // (E, D)
    float* __restrict__ out,
    unsigned* __restrict__ cnt,
    int* __restrict__ e0, int* __restrict__ e1,
    float* __restrict__ p0, float* __restrict__ p1)
{
    __shared__ union {
        float wl[EE * DD];                              // 32 KB (logits)
        struct { int se[KK * NT]; float sp[KK * NT]; } s2;  // 64 KB (rank)
    } u;
    __shared__ unsigned long long wsumA[WPB], wsumB[WPB];
    __shared__ int lastflag;

    const int tid  = threadIdx.x;
    const int wave = tid >> 6;
    const int lane = tid & 63;

    // ---------------- Phase 1: logits + top-2 + softmax ----------------
    for (int i = tid; i < EE * DD / 4; i += BT)
        reinterpret_cast<float4*>(u.wl)[i] = reinterpret_cast<const float4*>(w)[i];
    __syncthreads();

    const int wid = blockIdx.x * WPB + wave;            // 0..2047
    for (int t = wid; t < NT; t += NWAVE) {             // 2 tokens/wave
        const float4* xt = reinterpret_cast<const float4*>(x + (size_t)t * DD);
        float acc[EE];
        #pragma unroll
        for (int e = 0; e < EE; ++e) acc[e] = 0.0f;

        #pragma unroll
        for (int ii = 0; ii < DD / 4 / 64; ++ii) {      // 4 iters
            const int i = ii * 64 + lane;
            const float4 xv = xt[i];
            #pragma unroll
            for (int e = 0; e < EE; ++e) {
                const float4 wv = reinterpret_cast<const float4*>(u.wl + e * DD)[i];
                acc[e] += xv.x * wv.x + xv.y * wv.y + xv.z * wv.z + xv.w * wv.w;
            }
        }

        #pragma unroll
        for (int e = 0; e < EE; ++e) {
            float v = acc[e];
            #pragma unroll
            for (int off = 32; off > 0; off >>= 1) v += __shfl_xor(v, off);
            acc[e] = v;
        }

        if (lane == 0) {
            int b0 = 0; float l0 = acc[0];
            #pragma unroll
            for (int e = 1; e < EE; ++e) { if (acc[e] > l0) { l0 = acc[e]; b0 = e; } }
            int b1 = -1; float l1 = -INFINITY;
            #pragma unroll
            for (int e = 0; e < EE; ++e) { if (e != b0 && acc[e] > l1) { l1 = acc[e]; b1 = e; } }

            const float z  = expf(l1 - l0);             // l1 <= l0
            const float pa = 1.0f / (1.0f + z);
            const float pb = z * pa;

            e0[t] = b0; e1[t] = b1;
            p0[t] = pa; p1[t] = pb;
        }
    }

    // ---------------- Arrival: last block runs phase 2 ----------------
    __syncthreads();
    if (tid == 0) {
        const unsigned old = __hip_atomic_fetch_add(cnt, 1u, __ATOMIC_ACQ_REL,
                                                    __HIP_MEMORY_SCOPE_AGENT);
        lastflag = (old == GB - 1);
    }
    __syncthreads();
    if (!lastflag) return;

    // ---------------- Phase 2: ordered rank -> used_cap + scatter ----------
    #pragma unroll
    for (int k = 0; k < NT / BT; ++k) {                 // 4 iters
        const int i = k * BT + tid;
        u.s2.se[swz(i)]      = e0[i];
        u.s2.se[swz(NT + i)] = e1[i];
        u.s2.sp[swz(i)]      = p0[i];
        u.s2.sp[swz(NT + i)] = p1[i];
    }
    __syncthreads();

    const int base = tid * JPT;
    unsigned long long ca = 0ull, cb = 0ull;            // experts 0-3 / 4-7, 16b fields
    #pragma unroll
    for (int i = 0; i < JPT; ++i) {
        const int e = u.s2.se[swz(base + i)];
        if (e < 4) ca += 1ull << (16 * e);
        else       cb += 1ull << (16 * (e - 4));
    }

    unsigned long long sa = ca, sb = cb;                // intra-wave inclusive scan
    #pragma unroll
    for (int off = 1; off < 64; off <<= 1) {
        const unsigned long long ta = __shfl_up(sa, off);
        const unsigned long long tb = __shfl_up(sb, off);
        if ((tid & 63) >= off) { sa += ta; sb += tb; }
    }
    if ((tid & 63) == 63) { wsumA[wave] = sa; wsumB[wave] = sb; }
    __syncthreads();

    unsigned long long preA = 0ull, preB = 0ull;
    #pragma unroll
    for (int k = 0; k < WPB; ++k) {
        if (k < wave) { preA += wsumA[k]; preB += wsumB[k]; }
    }
    unsigned long long ra = preA + sa - ca;             // exclusive prefix
    unsigned long long rb = preB + sb - cb;

    // replay in ascending j order + scatter into the (already zeroed) output
    #pragma unroll
    for (int i = 0; i < JPT; ++i) {
        const int j = base + i;
        const int e = u.s2.se[swz(j)];
        int rank;
        if (e < 4) { rank = (int)((ra >> (16 * e)) & 0xFFFF);       ra += 1ull << (16 * e); }
        else       { rank = (int)((rb >> (16 * (e - 4))) & 0xFFFF); rb += 1ull << (16 * (e - 4)); }
        if (rank < CAP) {
            const float p = u.s2.sp[swz(j)];
            if (p != 0.0f) {                            // sec_mask == (cb_weight != 0)
                const int tt = j & (NT - 1);
                const size_t idx = (size_t)tt * (EE * CAP) + (size_t)e * CAP + (size_t)rank;
                out[8 + idx] = p;
                out[8 + (size_t)CBN + idx] = 1.0f;
            }
        }
    }

    // used_cap -> out[0..7]
    if (tid < EE) {
        unsigned long long totA = 0ull, totB = 0ull;
        #pragma unroll
        for (int k = 0; k < WPB; ++k) { totA += wsumA[k]; totB += wsumB[k]; }
        const int e = tid;
        const int tot = (e < 4) ? (int)((totA >> (16 * e)) & 0xFFFF)
                                : (int)((totB >> (16 * (e - 4))) & 0xFFFF);
        out[e] = (float)((tot < CAP) ? tot : CAP);
    }
}

// ---------------------------------------------------------------------------
extern "C" void kernel_launch(void* const* d_in, const int* in_sizes, int n_in,
                              void* d_out, int out_size, void* d_ws, size_t ws_size,
                              hipStream_t stream) {
    const float* x = (const float*)d_in[0];     // (B,T,D) f32
    const float* w = (const float*)d_in[1];     // (E,D)   f32
    float* out = (float*)d_out;

    char* ws = (char*)d_ws;
    unsigned* cnt = (unsigned*)(ws);            // 64 B arrival counter
    int*   e0 = (int*)(ws + 1 * 1024);          // 16 KB
    int*   e1 = (int*)(ws + 17 * 1024);         // 16 KB
    float* p0 = (float*)(ws + 33 * 1024);       // 16 KB
    float* p1 = (float*)(ws + 49 * 1024);       // 16 KB

    // zero the arrival counter each replay (tiny node, poison-proof)
    hipMemsetAsync(cnt, 0, 64, stream);

    // 1) rocclr-shape zero fill: no LDS, 1 plain f4 store/thread, 81920 blocks
    fill_kernel<<<FBLK, 256, 0, stream>>>(out);

    // 2) fused logits + (last-arrival) ordered rank/capacity/used_cap/scatter
    fused_k1k2_kernel<<<GB, BT, 0, stream>>>(x, w, out, cnt, e0, e1, p0, p1);
}

// Round 12
// 113.890 us; speedup vs baseline: 1.2275x; 1.0636x over previous
//
#include <hip/hip_runtime.h>
#include <hip/hip_bf16.h>
#include <math.h>

// Problem constants (static config in reference)
#define NT      4096              // B*T
#define DD      1024              // D
#define EE      8                 // experts
#define KK      2                 // top-k
#define CAP     1280              // EXP_CAP
#define CBN     (NT * EE * CAP)   // 41,943,040 elements per big output

#define GB      128               // fused K1K2 blocks
#define BT      1024              // threads per fused block (16 waves)
#define WPB     (BT / 64)         // 16
#define NWAVE   (GB * WPB)        // 2048 waves -> 2 tokens/wave
#define JPT     (KK * NT / BT)    // 8 assignments per thread (K2)

// LDS index swizzle (involution): spreads per-thread contiguous walks
// across banks.
__device__ __forceinline__ int swz(int j) { return j ^ ((j >> 5) & 31); }

// ---------------------------------------------------------------------------
// K1+K2 fused (validated rounds 10-11, absmax 0): logits/top2/softmax on all
// 128 blocks (2 tokens/wave), then the LAST block to arrive (ACQ_REL atomic)
// runs the ordered rank / capacity / used_cap / scatter (1024-thread version,
// validated rounds 8-11).
// ---------------------------------------------------------------------------
__global__ __launch_bounds__(BT) void fused_k1k2_kernel(
    const float* __restrict__ x,        // (NT, D)
    const float* __restrict__ w,        // (E, D)
    float* __restrict__ out,
    unsigned* __restrict__ cnt,
    int* __restrict__ e0, int* __restrict__ e1,
    float* __restrict__ p0, float* __restrict__ p1)
{
    __shared__ union {
        float wl[EE * DD];                              // 32 KB (logits)
        struct { int se[KK * NT]; float sp[KK * NT]; } s2;  // 64 KB (rank)
    } u;
    __shared__ unsigned long long wsumA[WPB], wsumB[WPB];
    __shared__ int lastflag;

    const int tid  = threadIdx.x;
    const int wave = tid >> 6;
    const int lane = tid & 63;

    // ---------------- Phase 1: logits + top-2 + softmax ----------------
    for (int i = tid; i < EE * DD / 4; i += BT)
        reinterpret_cast<float4*>(u.wl)[i] = reinterpret_cast<const float4*>(w)[i];
    __syncthreads();

    const int wid = blockIdx.x * WPB + wave;            // 0..2047
    for (int t = wid; t < NT; t += NWAVE) {             // 2 tokens/wave
        const float4* xt = reinterpret_cast<const float4*>(x + (size_t)t * DD);
        float acc[EE];
        #pragma unroll
        for (int e = 0; e < EE; ++e) acc[e] = 0.0f;

        #pragma unroll
        for (int ii = 0; ii < DD / 4 / 64; ++ii) {      // 4 iters
            const int i = ii * 64 + lane;
            const float4 xv = xt[i];
            #pragma unroll
            for (int e = 0; e < EE; ++e) {
                const float4 wv = reinterpret_cast<const float4*>(u.wl + e * DD)[i];
                acc[e] += xv.x * wv.x + xv.y * wv.y + xv.z * wv.z + xv.w * wv.w;
            }
        }

        #pragma unroll
        for (int e = 0; e < EE; ++e) {
            float v = acc[e];
            #pragma unroll
            for (int off = 32; off > 0; off >>= 1) v += __shfl_xor(v, off);
            acc[e] = v;
        }

        if (lane == 0) {
            int b0 = 0; float l0 = acc[0];
            #pragma unroll
            for (int e = 1; e < EE; ++e) { if (acc[e] > l0) { l0 = acc[e]; b0 = e; } }
            int b1 = -1; float l1 = -INFINITY;
            #pragma unroll
            for (int e = 0; e < EE; ++e) { if (e != b0 && acc[e] > l1) { l1 = acc[e]; b1 = e; } }

            const float z  = expf(l1 - l0);             // l1 <= l0
            const float pa = 1.0f / (1.0f + z);
            const float pb = z * pa;

            e0[t] = b0; e1[t] = b1;
            p0[t] = pa; p1[t] = pb;
        }
    }

    // ---------------- Arrival: last block runs phase 2 ----------------
    __syncthreads();
    if (tid == 0) {
        const unsigned old = __hip_atomic_fetch_add(cnt, 1u, __ATOMIC_ACQ_REL,
                                                    __HIP_MEMORY_SCOPE_AGENT);
        lastflag = (old == GB - 1);
    }
    __syncthreads();
    if (!lastflag) return;

    // ---------------- Phase 2: ordered rank -> used_cap + scatter ----------
    #pragma unroll
    for (int k = 0; k < NT / BT; ++k) {                 // 4 iters
        const int i = k * BT + tid;
        u.s2.se[swz(i)]      = e0[i];
        u.s2.se[swz(NT + i)] = e1[i];
        u.s2.sp[swz(i)]      = p0[i];
        u.s2.sp[swz(NT + i)] = p1[i];
    }
    __syncthreads();

    const int base = tid * JPT;
    unsigned long long ca = 0ull, cb = 0ull;            // experts 0-3 / 4-7, 16b fields
    #pragma unroll
    for (int i = 0; i < JPT; ++i) {
        const int e = u.s2.se[swz(base + i)];
        if (e < 4) ca += 1ull << (16 * e);
        else       cb += 1ull << (16 * (e - 4));
    }

    unsigned long long sa = ca, sb = cb;                // intra-wave inclusive scan
    #pragma unroll
    for (int off = 1; off < 64; off <<= 1) {
        const unsigned long long ta = __shfl_up(sa, off);
        const unsigned long long tb = __shfl_up(sb, off);
        if ((tid & 63) >= off) { sa += ta; sb += tb; }
    }
    if ((tid & 63) == 63) { wsumA[wave] = sa; wsumB[wave] = sb; }
    __syncthreads();

    unsigned long long preA = 0ull, preB = 0ull;
    #pragma unroll
    for (int k = 0; k < WPB; ++k) {
        if (k < wave) { preA += wsumA[k]; preB += wsumB[k]; }
    }
    unsigned long long ra = preA + sa - ca;             // exclusive prefix
    unsigned long long rb = preB + sb - cb;

    // replay in ascending j order + scatter into the (already zeroed) output
    #pragma unroll
    for (int i = 0; i < JPT; ++i) {
        const int j = base + i;
        const int e = u.s2.se[swz(j)];
        int rank;
        if (e < 4) { rank = (int)((ra >> (16 * e)) & 0xFFFF);       ra += 1ull << (16 * e); }
        else       { rank = (int)((rb >> (16 * (e - 4))) & 0xFFFF); rb += 1ull << (16 * (e - 4)); }
        if (rank < CAP) {
            const float p = u.s2.sp[swz(j)];
            if (p != 0.0f) {                            // sec_mask == (cb_weight != 0)
                const int tt = j & (NT - 1);
                const size_t idx = (size_t)tt * (EE * CAP) + (size_t)e * CAP + (size_t)rank;
                out[8 + idx] = p;
                out[8 + (size_t)CBN + idx] = 1.0f;
            }
        }
    }

    // used_cap -> out[0..7]
    if (tid < EE) {
        unsigned long long totA = 0ull, totB = 0ull;
        #pragma unroll
        for (int k = 0; k < WPB; ++k) { totA += wsumA[k]; totB += wsumB[k]; }
        const int e = tid;
        const int tot = (e < 4) ? (int)((totA >> (16 * e)) & 0xFFFF)
                                : (int)((totB >> (16 * (e - 4))) & 0xFFFF);
        out[e] = (float)((tot < CAP) ? tot : CAP);
    }
}

// ---------------------------------------------------------------------------
extern "C" void kernel_launch(void* const* d_in, const int* in_sizes, int n_in,
                              void* d_out, int out_size, void* d_ws, size_t ws_size,
                              hipStream_t stream) {
    const float* x = (const float*)d_in[0];     // (B,T,D) f32
    const float* w = (const float*)d_in[1];     // (E,D)   f32
    float* out = (float*)d_out;

    char* ws = (char*)d_ws;
    unsigned* cnt = (unsigned*)(ws);            // 64 B arrival counter
    int*   e0 = (int*)(ws + 1 * 1024);          // 16 KB
    int*   e1 = (int*)(ws + 17 * 1024);         // 16 KB
    float* p0 = (float*)(ws + 33 * 1024);       // 16 KB
    float* p1 = (float*)(ws + 49 * 1024);       // 16 KB

    // 1) zero the arrival counter (tiny node, poison-proof)
    hipMemsetAsync(cnt, 0, 64, stream);

    // 2) zero the entire output via the ROCclr fill path — measured strictly
    //    fastest (8.2 TB/s steady): every hand-fill variant (plain grid-stride,
    //    wave-row, nt, sc0sc1nt, 1-store/82k-blocks) measured 2.7-4.4 TB/s.
    hipMemsetAsync(d_out, 0, (size_t)out_size * sizeof(float), stream);

    // 3) fused logits + (last-arrival) ordered rank/capacity/used_cap/scatter
    fused_k1k2_kernel<<<GB, BT, 0, stream>>>(x, w, out, cnt, e0, e1, p0, p1);
}

// Round 13
// 79.202 us; speedup vs baseline: 1.7650x; 1.4380x over previous
//
#include <hip/hip_runtime.h>
#include <hip/hip_bf16.h>
#include <math.h>

// Problem constants (static config in reference)
#define NT      4096              // B*T
#define DD      1024              // D
#define EE      8                 // experts
#define KK      2                 // top-k
#define CAP     1280              // EXP_CAP
#define CBN     (NT * EE * CAP)   // 41,943,040 elements per big output

#define K2T     1024              // K2 threads (16 waves, one block)
#define JPT     (KK * NT / K2T)   // 8 assignments per thread

// LDS index swizzle (involution): spreads per-thread contiguous walks
// across banks (<=2-way aliasing for stride-8 and stride-32 walks).
__device__ __forceinline__ int swz(int j) { return j ^ ((j >> 5) & 31); }

// ---------------------------------------------------------------------------
// K1: router logits + top-2 + softmax(top-2). Wave per 2 tokens, w in LDS.
// (validated rounds 2-8, absmax 0)
// ---------------------------------------------------------------------------
__global__ __launch_bounds__(256) void logits_kernel(
    const float* __restrict__ x,        // (NT, D)
    const float* __restrict__ w,        // (E, D)
    int* __restrict__ e0, int* __restrict__ e1,
    float* __restrict__ p0, float* __restrict__ p1)
{
    __shared__ float wl[EE * DD];       // 32 KB

    for (int i = threadIdx.x; i < EE * DD / 4; i += 256)
        reinterpret_cast<float4*>(wl)[i] = reinterpret_cast<const float4*>(w)[i];
    __syncthreads();

    const int wave = threadIdx.x >> 6;
    const int lane = threadIdx.x & 63;
    const int wid  = blockIdx.x * 4 + wave;

    for (int t = wid; t < NT; t += gridDim.x * 4) {
        const float4* xt = reinterpret_cast<const float4*>(x + (size_t)t * DD);
        float acc[EE];
        #pragma unroll
        for (int e = 0; e < EE; ++e) acc[e] = 0.0f;

        #pragma unroll
        for (int ii = 0; ii < DD / 4 / 64; ++ii) {      // 4 iters
            const int i = ii * 64 + lane;
            const float4 xv = xt[i];
            #pragma unroll
            for (int e = 0; e < EE; ++e) {
                const float4 wv = reinterpret_cast<const float4*>(wl + e * DD)[i];
                acc[e] += xv.x * wv.x + xv.y * wv.y + xv.z * wv.z + xv.w * wv.w;
            }
        }

        #pragma unroll
        for (int e = 0; e < EE; ++e) {
            float v = acc[e];
            #pragma unroll
            for (int off = 32; off > 0; off >>= 1) v += __shfl_xor(v, off);
            acc[e] = v;
        }

        if (lane == 0) {
            int b0 = 0; float l0 = acc[0];
            #pragma unroll
            for (int e = 1; e < EE; ++e) { if (acc[e] > l0) { l0 = acc[e]; b0 = e; } }
            int b1 = -1; float l1 = -INFINITY;
            #pragma unroll
            for (int e = 0; e < EE; ++e) { if (e != b0 && acc[e] > l1) { l1 = acc[e]; b1 = e; } }

            const float z  = expf(l1 - l0);     // l1 <= l0
            const float pa = 1.0f / (1.0f + z);
            const float pb = z * pa;

            e0[t] = b0; e1[t] = b1;
            p0[t] = pa; p1[t] = pb;
        }
    }
}

// ---------------------------------------------------------------------------
// K2: fused ordered rank / capacity drop / used_cap / scatter.
// One block, 1024 threads (16 waves). (validated round 8, absmax 0)
// ---------------------------------------------------------------------------
__global__ __launch_bounds__(K2T) void rank_scatter_kernel(
    const int* __restrict__ e0, const int* __restrict__ e1,
    const float* __restrict__ p0, const float* __restrict__ p1,
    float* __restrict__ out)
{
    __shared__ int   se[KK * NT];       // 32 KB, swizzled
    __shared__ float sp[KK * NT];       // 32 KB, swizzled
    __shared__ unsigned long long wsumA[16], wsumB[16];

    const int tid = threadIdx.x;

    // coalesced stage
    #pragma unroll
    for (int k = 0; k < NT / K2T; ++k) {            // 4 iters
        const int i = k * K2T + tid;
        se[swz(i)]      = e0[i];
        se[swz(NT + i)] = e1[i];
        sp[swz(i)]      = p0[i];
        sp[swz(NT + i)] = p1[i];
    }
    __syncthreads();

    const int base = tid * JPT;
    unsigned long long ca = 0ull, cb = 0ull;        // experts 0-3 / 4-7, 16b fields
    #pragma unroll
    for (int i = 0; i < JPT; ++i) {
        const int e = se[swz(base + i)];
        if (e < 4) ca += 1ull << (16 * e);
        else       cb += 1ull << (16 * (e - 4));
    }

    // intra-wave inclusive scan
    unsigned long long sa = ca, sb = cb;
    #pragma unroll
    for (int off = 1; off < 64; off <<= 1) {
        const unsigned long long ta = __shfl_up(sa, off);
        const unsigned long long tb = __shfl_up(sb, off);
        if ((tid & 63) >= off) { sa += ta; sb += tb; }
    }
    const int wv = tid >> 6;                        // 0..15
    if ((tid & 63) == 63) { wsumA[wv] = sa; wsumB[wv] = sb; }
    __syncthreads();

    unsigned long long preA = 0ull, preB = 0ull;
    #pragma unroll
    for (int k = 0; k < 16; ++k) {
        if (k < wv) { preA += wsumA[k]; preB += wsumB[k]; }
    }
    unsigned long long ra = preA + sa - ca;         // exclusive prefix, this thread
    unsigned long long rb = preB + sb - cb;

    // replay in ascending j order + scatter
    #pragma unroll
    for (int i = 0; i < JPT; ++i) {
        const int j = base + i;
        const int e = se[swz(j)];
        int rank;
        if (e < 4) { rank = (int)((ra >> (16 * e)) & 0xFFFF);       ra += 1ull << (16 * e); }
        else       { rank = (int)((rb >> (16 * (e - 4))) & 0xFFFF); rb += 1ull << (16 * (e - 4)); }
        if (rank < CAP) {
            const float p = sp[swz(j)];
            if (p != 0.0f) {                        // sec_mask == (cb_weight != 0)
                const int t = j & (NT - 1);
                const size_t idx = (size_t)t * (EE * CAP) + (size_t)e * CAP + (size_t)rank;
                out[8 + idx] = p;
                out[8 + (size_t)CBN + idx] = 1.0f;
            }
        }
    }

    // used_cap
    if (tid < EE) {
        unsigned long long totA = 0ull, totB = 0ull;
        #pragma unroll
        for (int k = 0; k < 16; ++k) { totA += wsumA[k]; totB += wsumB[k]; }
        const int e = tid;
        const int tot = (e < 4) ? (int)((totA >> (16 * e)) & 0xFFFF)
                                : (int)((totB >> (16 * (e - 4))) & 0xFFFF);
        out[e] = (float)((tot < CAP) ? tot : CAP);
    }
}

// ---------------------------------------------------------------------------
extern "C" void kernel_launch(void* const* d_in, const int* in_sizes, int n_in,
                              void* d_out, int out_size, void* d_ws, size_t ws_size,
                              hipStream_t stream) {
    const float* x = (const float*)d_in[0];     // (B,T,D) f32
    const float* w = (const float*)d_in[1];     // (E,D)   f32
    float* out = (float*)d_out;

    char* ws = (char*)d_ws;
    int*   e0 = (int*)(ws);                     // 16 KB
    int*   e1 = (int*)(ws + 16 * 1024);         // 16 KB
    float* p0 = (float*)(ws + 32 * 1024);       // 16 KB
    float* p1 = (float*)(ws + 48 * 1024);       // 16 KB

    // 1) zero the entire output via the ROCclr fill path (~7-8 TB/s).
    //    Every hand-fill variant measured slower (2.7-4.4 TB/s): plain
    //    grid-stride, wave-row, nontemporal, sc0sc1nt, 1-store/82k-blocks.
    hipMemsetAsync(d_out, 0, (size_t)out_size * sizeof(float), stream);

    // 2) router logits + top-2 + softmax (512 blocks)
    logits_kernel<<<512, 256, 0, stream>>>(x, w, e0, e1, p0, p1);

    // 3) fused ordered rank + capacity + used_cap + scatter (1 block, 16 waves)
    rank_scatter_kernel<<<1, K2T, 0, stream>>>(e0, e1, p0, p1, out);
}